// Round 1
// baseline (229.412 us; speedup 1.0000x reference)
//
#include <hip/hip_runtime.h>

// HGCN on MI355X. logmap0(expmap0(v)) == v here, so the model reduces to:
//   t1 = sigmoid(segmean(feat@W1+b1)); t2 = sigmoid(segmean(t1@W2+b2))
//   out = relu(t2@W3+b3)@W4 + b4     (segmean commutes with the linear map;
//   deg-0 nodes: segmean = 0 -> value 0.5 exactly, handled via dz check)
// R1: fp32 atomicAdd scatter = atomic wall -> counting-sort CSR + gather.
// R2: single-block scan = latency wall -> hierarchical scan.
// R3: 4B random scatter write-allocates 64B lines -> coarse buckets.
// R4: global atomics on few counters = contention wall -> LDS-staged radix.
// R5: agg gather byte-bound -> bf16 rows, pack CSR.
// R6: fp32 MLP LDS-bound -> MFMA epilogue.
// R8: aggregate before GEMM (linearity); bf16 MFMA everywhere.
// R11: frag-packed weight image -> B operands from global (L1-hot), no
//   weight LDS. R12: re-fused gather, but 26.6KB LDS -> 6 blocks/CU, 32% occ.
// R13: whole pipeline made WAVE-LOCAL (wave w owns rows w*16..+15, incl.
//   gather) -> ZERO barriers; split-K phase2 halves H3 -> 18.4KB LDS ->
//   8 blocks/CU. prep merged into part_a launch.
// R14: infra-failure rerun (container died twice; no counters). Kernel kept
//   structurally identical to the 226.9us best to re-anchor the baseline;
//   only change: v_rcp_f32 for the 1/deg in the gather epilogue (error
//   2^-22, absorbed by bf16 store). Counters will arbitrate between the
//   three queued candidates (csr_fine split / wave-per-row gather /
//   deeper ssrc prefetch).

constexpr int CSHIFT = 9;               // 512 nodes per coarse bucket
constexpr int CNODES = 1 << CSHIFT;
constexpr int EPB    = 4096;            // edges per partition block
constexpr int EPT    = EPB / 256;
constexpr int CAP    = 16384;           // arena capacity per bucket (mean 8163)

// frag-packed bf16 weight image (shorts). Fragment = 16 lanes x 8 shorts =
// 128 shorts; flat idx = (((c*KK + kk)*4 + quad)*16 + m)*8 + j.
constexpr int W1F_OFF = 0;              // 4x2x4 frags  = 4096 shorts
constexpr int W2F_OFF = 4096;           // 4096
constexpr int W3F_OFF = 8192;           // 8x2x4 frags  = 8192
constexpr int W4F_OFF = 16384;          // 3x4x4 frags  = 6144 (cols padded 48)
constexpr int WIMG_TOT = 22528;

typedef __attribute__((ext_vector_type(8))) short short8;   // 8 bf16
typedef __attribute__((ext_vector_type(4))) float floatx4;  // MFMA acc

__device__ __forceinline__ float sigmoidf(float x) {
    return 1.0f / (1.0f + __expf(-x));
}
__device__ __forceinline__ unsigned short f2bf(float f) {   // RNE f32->bf16
    unsigned int u = __float_as_uint(f);
    u = (u + 0x7FFFu + ((u >> 16) & 1u)) >> 16;
    return (unsigned short)u;
}

// ---------------- CSR partition + one-time prep (merged launch) ------------
// Blocks [0,gP): radix-partition edges into per-bucket arena regions.
// Blocks [gP,..): feat fp32->bf16 cast + frag-packed weight image build.
__global__ __launch_bounds__(256) void part_prep_k(
    const int* __restrict__ src, const int* __restrict__ dst,
    int* __restrict__ ccur, int* __restrict__ arena, int E, int NBUCK, int gP,
    const float* __restrict__ feat, unsigned short* __restrict__ featbf,
    const float* __restrict__ W1, const float* __restrict__ W2,
    const float* __restrict__ W3, const float* __restrict__ W4,
    unsigned short* __restrict__ img, int n8)
{
    __shared__ int  hist[256];
    __shared__ int  exoff[256];
    __shared__ int  lcur[256];
    __shared__ int  gbase[256];
    __shared__ int  stage[EPB];
    __shared__ unsigned char stageB[EPB];

    const int tid = threadIdx.x;

    if ((int)blockIdx.x >= gP) {
        // ---- prep path ----
        int i = ((int)blockIdx.x - gP) * 256 + tid;
        if (i < n8) {
            const float4* p = (const float4*)feat + (size_t)i * 2;
            float4 a = p[0], b = p[1];
            uint4 o;
            o.x = (unsigned)f2bf(a.x) | ((unsigned)f2bf(a.y) << 16);
            o.y = (unsigned)f2bf(a.z) | ((unsigned)f2bf(a.w) << 16);
            o.z = (unsigned)f2bf(b.x) | ((unsigned)f2bf(b.y) << 16);
            o.w = (unsigned)f2bf(b.z) | ((unsigned)f2bf(b.w) << 16);
            ((uint4*)featbf)[i] = o;
            return;
        }
        int t = i - n8;
        if (t >= WIMG_TOT) return;
        float v = 0.f;
        int s = t;
        if (s < W2F_OFF) {                       // W1 [64x64]
            int j = s & 7, m = (s >> 3) & 15, q = (s >> 7) & 3, kk = (s >> 9) & 1, c = s >> 10;
            v = W1[(kk * 32 + q * 8 + j) * 64 + c * 16 + m];
        } else if (s < W3F_OFF) {                // W2 [64x64]
            s -= W2F_OFF;
            int j = s & 7, m = (s >> 3) & 15, q = (s >> 7) & 3, kk = (s >> 9) & 1, c = s >> 10;
            v = W2[(kk * 32 + q * 8 + j) * 64 + c * 16 + m];
        } else if (s < W4F_OFF) {                // W3 [64x128]
            s -= W3F_OFF;
            int j = s & 7, m = (s >> 3) & 15, q = (s >> 7) & 3, kk = (s >> 9) & 1, c = s >> 10;
            v = W3[(kk * 32 + q * 8 + j) * 128 + c * 16 + m];
        } else {                                 // W4 [128x40], cols padded 48
            s -= W4F_OFF;
            int j = s & 7, m = (s >> 3) & 15, q = (s >> 7) & 3, kk = (s >> 9) & 3, c = s >> 11;
            int n = c * 16 + m;
            if (n < 40) v = W4[(kk * 32 + q * 8 + j) * 40 + n];
        }
        img[t] = f2bf(v);
        return;
    }

    // ---- partition path ----
    const int e0  = blockIdx.x * EPB;
    const int ec  = min(EPB, E - e0);

    int pk[EPT], bk[EPT];
    hist[tid] = 0;
    __syncthreads();
    #pragma unroll
    for (int j = 0; j < EPT; j++) {
        int idx = tid + j * 256;
        if (idx < ec) {
            int s = src[e0 + idx];
            int d = dst[e0 + idx];
            bk[j] = d >> CSHIFT;
            pk[j] = s | ((d & (CNODES - 1)) << 17);
            atomicAdd(&hist[bk[j]], 1);
        } else bk[j] = -1;
    }
    __syncthreads();
    const int h = hist[tid];
    exoff[tid] = h;
    __syncthreads();
    for (int dd = 1; dd < 256; dd <<= 1) {
        int v = 0;
        if (tid >= dd) v = exoff[tid - dd];
        __syncthreads();
        if (tid >= dd) exoff[tid] += v;
        __syncthreads();
    }
    const int ex = exoff[tid] - h;
    int gb = 0;
    if (tid < NBUCK && h > 0) gb = atomicAdd(ccur + tid, h);
    __syncthreads();
    exoff[tid] = ex;
    lcur[tid]  = ex;
    gbase[tid] = gb;
    __syncthreads();
    #pragma unroll
    for (int j = 0; j < EPT; j++) {
        if (bk[j] >= 0) {
            int l = atomicAdd(&lcur[bk[j]], 1);
            stage[l]  = pk[j];
            stageB[l] = (unsigned char)bk[j];
        }
    }
    __syncthreads();
    for (int i = tid; i < ec; i += 256) {
        int b = stageB[i];
        arena[(size_t)b * CAP + gbase[b] + (i - exoff[b])] = stage[i];
    }
}

// One block per coarse bucket: inline scan of bucket counts -> cbeg; then
// LDS counting sort over 512 nodes -> off/ssrc.
__global__ __launch_bounds__(256) void csr_fine(const int* __restrict__ arena,
                                                const int* __restrict__ ccur,
                                                int* __restrict__ off,
                                                int* __restrict__ ssrc,
                                                int N, int E, int NBUCK) {
    __shared__ int cnt[CNODES];
    __shared__ int cur[CNODES];
    __shared__ int part[256];
    const int b = blockIdx.x;
    const int node0 = b << CSHIFT;
    const int tid = threadIdx.x;

    part[tid] = (tid < NBUCK) ? ccur[tid] : 0;
    __syncthreads();
    for (int d = 1; d < 256; d <<= 1) {
        int v = 0;
        if (tid >= d) v = part[tid - d];
        __syncthreads();
        if (tid >= d) part[tid] += v;
        __syncthreads();
    }
    const int cbeg = (b > 0) ? part[b - 1] : 0;
    const int ec   = ccur[b];
    if (b == 0 && tid == 0) off[N] = E;
    __syncthreads();

    const int* pe = arena + (size_t)b * CAP;
    cnt[tid] = 0;
    cnt[tid + 256] = 0;
    __syncthreads();
    for (int i = tid; i < ec; i += 256)
        atomicAdd(&cnt[(pe[i] >> 17) & (CNODES - 1)], 1);
    __syncthreads();
    const int c0 = cnt[2 * tid], c1 = cnt[2 * tid + 1];
    part[tid] = c0 + c1;
    __syncthreads();
    for (int d = 1; d < 256; d <<= 1) {
        int v = 0;
        if (tid >= d) v = part[tid - d];
        __syncthreads();
        if (tid >= d) part[tid] += v;
        __syncthreads();
    }
    const int ex = (tid > 0) ? part[tid - 1] : 0;
    cur[2 * tid]     = ex;
    cur[2 * tid + 1] = ex + c0;
    if (node0 + 2 * tid     < N) off[node0 + 2 * tid]     = cbeg + ex;
    if (node0 + 2 * tid + 1 < N) off[node0 + 2 * tid + 1] = cbeg + ex + c0;
    __syncthreads();
    for (int i = tid; i < ec; i += 256) {
        int p = pe[i];
        int pos = cbeg + atomicAdd(&cur[(p >> 17) & (CNODES - 1)], 1);
        ssrc[pos] = p & 0x1FFFF;
    }
}

// ---------------- wave-local gather: mean of h[src] rows into LDS tile -----
// Wave w gathers ITS OWN rows w*16..w*16+15 (2 passes x 8 rows x 8 lanes).
// All later reads of Agg by wave w hit only these rows -> no barrier needed.
#define ACC8(v)                                    \
    acc[0] += __uint_as_float((v).x << 16);        \
    acc[1] += __uint_as_float((v).x & 0xFFFF0000u);\
    acc[2] += __uint_as_float((v).y << 16);        \
    acc[3] += __uint_as_float((v).y & 0xFFFF0000u);\
    acc[4] += __uint_as_float((v).z << 16);        \
    acc[5] += __uint_as_float((v).z & 0xFFFF0000u);\
    acc[6] += __uint_as_float((v).w << 16);        \
    acc[7] += __uint_as_float((v).w & 0xFFFF0000u);

__device__ __forceinline__ void gather_tile_wave(
    const unsigned short* __restrict__ h, const int* __restrict__ off,
    const int* __restrict__ ssrc, unsigned short* Agg, int rowB, int N,
    int w, int lane)
{
    #pragma unroll
    for (int pass = 0; pass < 2; pass++) {
        int rl = w * 16 + pass * 8 + (lane >> 3);
        int g  = rowB + rl;
        int q  = (lane & 7) * 8;
        uint4 p = make_uint4(0u, 0u, 0u, 0u);
        if (g < N) {
            int beg = off[g], end = off[g + 1];
            float acc[8] = {0.f, 0.f, 0.f, 0.f, 0.f, 0.f, 0.f, 0.f};
            int i = beg;
            for (; i + 8 <= end; i += 8) {       // 8 loads in flight per lane
                uint4 v0 = *(const uint4*)(h + (size_t)ssrc[i]     * 64 + q);
                uint4 v1 = *(const uint4*)(h + (size_t)ssrc[i + 1] * 64 + q);
                uint4 v2 = *(const uint4*)(h + (size_t)ssrc[i + 2] * 64 + q);
                uint4 v3 = *(const uint4*)(h + (size_t)ssrc[i + 3] * 64 + q);
                uint4 v4 = *(const uint4*)(h + (size_t)ssrc[i + 4] * 64 + q);
                uint4 v5 = *(const uint4*)(h + (size_t)ssrc[i + 5] * 64 + q);
                uint4 v6 = *(const uint4*)(h + (size_t)ssrc[i + 6] * 64 + q);
                uint4 v7 = *(const uint4*)(h + (size_t)ssrc[i + 7] * 64 + q);
                ACC8(v0); ACC8(v1); ACC8(v2); ACC8(v3);
                ACC8(v4); ACC8(v5); ACC8(v6); ACC8(v7);
            }
            for (; i + 2 <= end; i += 2) {
                uint4 v0 = *(const uint4*)(h + (size_t)ssrc[i]     * 64 + q);
                uint4 v1 = *(const uint4*)(h + (size_t)ssrc[i + 1] * 64 + q);
                ACC8(v0); ACC8(v1);
            }
            for (; i < end; i++) {
                uint4 v = *(const uint4*)(h + (size_t)ssrc[i] * 64 + q);
                ACC8(v);
            }
            // v_rcp_f32: 2^-22 rel err, absorbed by the bf16 round (R14)
            float inv = __builtin_amdgcn_rcpf((float)max(end - beg, 1));
            p.x = (unsigned)f2bf(acc[0]*inv) | ((unsigned)f2bf(acc[1]*inv) << 16);
            p.y = (unsigned)f2bf(acc[2]*inv) | ((unsigned)f2bf(acc[3]*inv) << 16);
            p.z = (unsigned)f2bf(acc[4]*inv) | ((unsigned)f2bf(acc[5]*inv) << 16);
            p.w = (unsigned)f2bf(acc[6]*inv) | ((unsigned)f2bf(acc[7]*inv) << 16);
        }
        *(uint4*)(Agg + rl * 72 + q) = p;
    }
}

// ---------------- fused gather + GEMM1 + sigmoid -> t1 (9KB LDS, 0 barriers)
__global__ __launch_bounds__(256) void aggemm1_k(
    const unsigned short* __restrict__ featbf, const int* __restrict__ off,
    const int* __restrict__ ssrc, const unsigned short* __restrict__ img,
    const float* __restrict__ bias, unsigned short* __restrict__ t1, int N)
{
    __shared__ alignas(16) unsigned short Agg[64 * 72];   // 9.2 KB

    const int tid = threadIdx.x;
    const int rowB = blockIdx.x * 64;
    const int w = tid >> 6, lane = tid & 63;
    const int m = lane & 15, quad = lane >> 4;
    const int row0 = rowB + w * 16;

    gather_tile_wave(featbf, off, ssrc, Agg, rowB, N, w, lane);

    const short8* Wf = (const short8*)(img + W1F_OFF);
    floatx4 acc[4];
    #pragma unroll
    for (int c = 0; c < 4; c++) acc[c] = (floatx4){0.f, 0.f, 0.f, 0.f};
    #pragma unroll
    for (int kk = 0; kk < 2; kk++) {
        short8 a = *(const short8*)(Agg + (w * 16 + m) * 72 + kk * 32 + quad * 8);
        #pragma unroll
        for (int c = 0; c < 4; c++) {
            short8 b = Wf[((c * 2 + kk) * 4 + quad) * 16 + m];
            acc[c] = __builtin_amdgcn_mfma_f32_16x16x32_bf16(a, b, acc[c], 0, 0, 0);
        }
    }
    bool dzr[4];
    int rows[4];
    #pragma unroll
    for (int r = 0; r < 4; r++) {
        rows[r] = row0 + quad * 4 + r;
        dzr[r] = (rows[r] < N) ? (off[rows[r] + 1] == off[rows[r]]) : false;
    }
    #pragma unroll
    for (int c = 0; c < 4; c++) {
        int col = c * 16 + m;
        float bv = bias[col];
        #pragma unroll
        for (int r = 0; r < 4; r++) {
            if (rows[r] < N) {
                float v = dzr[r] ? 0.5f : sigmoidf(acc[c][r] + bv);
                t1[(size_t)rows[r] * 64 + col] = f2bf(v);
            }
        }
    }
}

// ---------------- fused gather + triple-GEMM -> out (18.4KB LDS, 0 barriers)
// LDS: T2[0,4608) | Agg/H3half[4608,9216). Split-K phase2 over two H3 halves.
// Every LDS row is touched only by its owning wave -> in-wave ordering
// (lgkmcnt) is sufficient, no __syncthreads anywhere.
__global__ __launch_bounds__(256) void aggep3_k(
    const unsigned short* __restrict__ t1, const int* __restrict__ off,
    const int* __restrict__ ssrc, const unsigned short* __restrict__ img,
    const float* __restrict__ b2, const float* __restrict__ b3,
    const float* __restrict__ b4, float* __restrict__ out, int N)
{
    __shared__ alignas(16) unsigned short SM[9216];   // 18.4 KB
    unsigned short* T2  = SM;            // 64 x 72
    unsigned short* Agg = SM + 4608;     // 64 x 72 (dead after phase 0)
    unsigned short* H3h = SM + 4608;     // 64 x 72 (aliases Agg)

    const int tid = threadIdx.x;
    const int rowB = blockIdx.x * 64;
    const int w = tid >> 6, lane = tid & 63;
    const int m = lane & 15, quad = lane >> 4;
    const int row0 = rowB + w * 16;

    gather_tile_wave(t1, off, ssrc, Agg, rowB, N, w, lane);

    // ---- phase 0: T2 = sigmoid(Agg @ W2 + b2) ----
    {
        const short8* Wf = (const short8*)(img + W2F_OFF);
        floatx4 acc[4];
        #pragma unroll
        for (int c = 0; c < 4; c++) acc[c] = (floatx4){0.f, 0.f, 0.f, 0.f};
        #pragma unroll
        for (int kk = 0; kk < 2; kk++) {
            short8 a = *(const short8*)(Agg + (w * 16 + m) * 72 + kk * 32 + quad * 8);
            #pragma unroll
            for (int c = 0; c < 4; c++) {
                short8 b = Wf[((c * 2 + kk) * 4 + quad) * 16 + m];
                acc[c] = __builtin_amdgcn_mfma_f32_16x16x32_bf16(a, b, acc[c], 0, 0, 0);
            }
        }
        bool dzr[4];
        #pragma unroll
        for (int r = 0; r < 4; r++) {
            int row = row0 + quad * 4 + r;
            dzr[r] = (row < N) ? (off[row + 1] == off[row]) : false;
        }
        #pragma unroll
        for (int c = 0; c < 4; c++) {
            int col = c * 16 + m;
            float bv = b2[col];
            #pragma unroll
            for (int r = 0; r < 4; r++) {
                int rl = w * 16 + quad * 4 + r;
                float v = dzr[r] ? 0.5f : sigmoidf(acc[c][r] + bv);
                T2[rl * 72 + col] = f2bf(v);
            }
        }
    }

    // ---- phases 1&2 split-K: per half, H3h = relu(T2@W3half+b3half),
    //      then acc2 += H3h @ W4[khalf] ----
    floatx4 acc2[3];
    #pragma unroll
    for (int c = 0; c < 3; c++) acc2[c] = (floatx4){0.f, 0.f, 0.f, 0.f};
    const short8* Wf3 = (const short8*)(img + W3F_OFF);
    const short8* Wf4 = (const short8*)(img + W4F_OFF);

    #pragma unroll
    for (int half = 0; half < 2; half++) {
        floatx4 acc[4];
        #pragma unroll
        for (int c = 0; c < 4; c++) acc[c] = (floatx4){0.f, 0.f, 0.f, 0.f};
        #pragma unroll
        for (int kk = 0; kk < 2; kk++) {
            short8 a = *(const short8*)(T2 + (w * 16 + m) * 72 + kk * 32 + quad * 8);
            #pragma unroll
            for (int c = 0; c < 4; c++) {
                short8 b = Wf3[(((half * 4 + c) * 2 + kk) * 4 + quad) * 16 + m];
                acc[c] = __builtin_amdgcn_mfma_f32_16x16x32_bf16(a, b, acc[c], 0, 0, 0);
            }
        }
        #pragma unroll
        for (int c = 0; c < 4; c++) {
            int col = c * 16 + m;
            float bv = b3[half * 64 + col];
            #pragma unroll
            for (int r = 0; r < 4; r++) {
                int rl = w * 16 + quad * 4 + r;
                H3h[rl * 72 + col] = f2bf(fmaxf(acc[c][r] + bv, 0.f));
            }
        }
        #pragma unroll
        for (int kk2 = 0; kk2 < 2; kk2++) {
            short8 a = *(const short8*)(H3h + (w * 16 + m) * 72 + kk2 * 32 + quad * 8);
            #pragma unroll
            for (int c = 0; c < 3; c++) {
                short8 b = Wf4[((c * 4 + half * 2 + kk2) * 4 + quad) * 16 + m];
                acc2[c] = __builtin_amdgcn_mfma_f32_16x16x32_bf16(a, b, acc2[c], 0, 0, 0);
            }
        }
    }

    // ---- store out = acc2 + b4 ----
    #pragma unroll
    for (int c = 0; c < 3; c++) {
        int col = c * 16 + m;
        if (col < 40) {
            float bv = b4[col];
            #pragma unroll
            for (int r = 0; r < 4; r++) {
                int row = row0 + quad * 4 + r;
                if (row < N) out[(size_t)row * 40 + col] = acc2[c][r] + bv;
            }
        }
    }
}

extern "C" void kernel_launch(void* const* d_in, const int* in_sizes, int n_in,
                              void* d_out, int out_size, void* d_ws, size_t ws_size,
                              hipStream_t stream)
{
    const float* feat = (const float*)d_in[0];
    const int*   eidx = (const int*)d_in[1];
    const float* W1 = (const float*)d_in[2];
    const float* b1 = (const float*)d_in[3];
    const float* W2 = (const float*)d_in[4];
    const float* b2 = (const float*)d_in[5];
    const float* W3 = (const float*)d_in[6];
    const float* b3 = (const float*)d_in[7];
    const float* W4 = (const float*)d_in[8];
    const float* b4 = (const float*)d_in[9];

    const int N = in_sizes[0] / 64;
    const int E = in_sizes[1] / 2;
    const int* src = eidx;
    const int* dst = eidx + E;

    const int NBUCK = (N + CNODES - 1) / CNODES;   // 196

    unsigned short* featbf = (unsigned short*)d_ws;            // N*64 bf16
    unsigned short* t1     = featbf + (size_t)N * 64;          // N*64 bf16
    unsigned short* img    = t1     + (size_t)N * 64;          // WIMG_TOT
    int*   off   = (int*)(img + WIMG_TOT);                     // N+1
    int*   ccur  = off + (N + 1);                              // NBUCK
    int*   ssrc  = ccur + NBUCK;                               // E
    int*   arena = ssrc + E;                                   // NBUCK*CAP
    float* out   = (float*)d_out;

    hipMemsetAsync(ccur, 0, (size_t)NBUCK * sizeof(int), stream);

    const dim3 blk(256);
    const int gP  = (E + EPB - 1) / EPB;
    const int g64 = (N + 63) / 64;
    const int n8  = N * 64 / 8;
    const int gPC = (n8 + WIMG_TOT + 255) / 256;

    // CSR partition + prep (merged), then per-bucket counting sort
    part_prep_k<<<gP + gPC, blk, 0, stream>>>(src, dst, ccur, arena, E, NBUCK,
                                              gP, feat, featbf, W1, W2, W3, W4,
                                              img, n8);
    csr_fine<<<NBUCK, blk, 0, stream>>>(arena, ccur, off, ssrc, N, E, NBUCK);

    // t1 = sigmoid(mean(featbf[src]) @ W1 + b1)   [fused, 0 barriers]
    aggemm1_k<<<g64, blk, 0, stream>>>(featbf, off, ssrc, img, b1, t1, N);
    // out = relu(sigmoid(mean(t1[src])@W2+b2)@W3+b3)@W4 + b4  [fused, 0 barriers]
    aggep3_k<<<g64, blk, 0, stream>>>(t1, off, ssrc, img, b2, b3, b4, out, N);
}